// Round 5
// baseline (64.535 us; speedup 1.0000x reference)
//
#include <hip/hip_runtime.h>
#include <math.h>

// out[b,i,h,w] = Ar[b,h,i]*cos(2*pi*i*w/128)/128 - Ai[b,h,i]*sin(2*pi*i*w/128)/128
// A = row-DFT of x (fft2 then ifft over H == fft over W only). mask unused.
// x real => out[b,128-i,:,:] == out[b,i,:,:] EXACTLY -> compute i=0..64 only,
// store each plane to both i and 128-i.
//
// v4: x half-row in registers (coalesced-enough float4 loads, L2-resident);
// DFT trig via 128-entry LDS table with WAVE-BROADCAST reads (phase index is
// lane-uniform up to `half`); A staged through tiny LDS (one barrier); store
// phase identical in spirit to the proven v2 path: plain (non-NT) float4
// stores, fully coalesced, no shfl on the store critical path.
// Grid: 1024 blocks = 32 b x 32 groups; group g: i in {2g,2g+1} (+ i=64 for g=31).

typedef float f32x4 __attribute__((ext_vector_type(4)));

__global__ __launch_bounds__(256, 4) void kspace_v4(const float* __restrict__ x,
                                                    float* __restrict__ out) {
    const int blk  = blockIdx.x;       // 0..1023
    const int b    = blk >> 5;
    const int g    = blk & 31;
    const int t    = threadIdx.x;
    const int wv   = t >> 6;           // wave 0..3
    const int lane = t & 63;
    const int h    = wv * 32 + (lane >> 1);   // this thread's DFT row
    const int half = lane & 1;                // which 64-u half of the row

    __shared__ __align__(16) float ct[128], st[128];        // cos/sin(2*pi*k/128)
    __shared__ __align__(16) float arL[3][128], aiL[3][128]; // A/W per i-slot

    if (t < 128) {
        float s, c;
        sincospif((float)t * (1.0f / 64.0f), &s, &c);   // angle pi*(t/64)
        ct[t] = c;
        st[t] = s;
    }

    // ---- load my half-row (64 floats, contiguous 256 B) into registers ----
    const float* xp = x + ((size_t)b * 128 + h) * 128 + half * 64;
    float xs[64];
#pragma unroll
    for (int j = 0; j < 16; ++j) {
        const f32x4 v = ((const f32x4*)xp)[j];
        xs[4 * j + 0] = v.x;
        xs[4 * j + 1] = v.y;
        xs[4 * j + 2] = v.z;
        xs[4 * j + 3] = v.w;
    }
    __syncthreads();   // trig tables ready

    const int nI = (g == 31) ? 3 : 2;

    // ---- DFT phase: A[i][h] = sum_u x[h][u] * e^{-2*pi*I*i*u/128} ----
#pragma unroll 1
    for (int ii = 0; ii < nI; ++ii) {
        const int i = g * 2 + ii;
        float ar = 0.0f, aiv = 0.0f;
        const int u0 = half * 64;
#pragma unroll
        for (int j = 0; j < 64; ++j) {
            const int k = (i * (u0 + j)) & 127;   // lane-uniform up to `half` -> broadcast read
            const float xv = xs[j];
            ar  = fmaf(xv,  ct[k], ar);
            aiv = fmaf(xv, -st[k], aiv);          // Im(fft) = -sum x*sin
        }
        ar  += __shfl_xor(ar, 1);
        aiv += __shfl_xor(aiv, 1);
        if (half == 0) {
            arL[ii][h] = ar  * (1.0f / 128.0f);
            aiL[ii][h] = aiv * (1.0f / 128.0f);
        }
    }
    __syncthreads();   // A ready; no further barriers

    // ---- store phase: planes (b,i) and exact duplicate (b,128-i) ----
#pragma unroll 1
    for (int ii = 0; ii < nI; ++ii) {
        const int i = g * 2 + ii;

        // per-lane trig for its fixed 4 w-columns (exact table lookup)
        const int wbase = (lane & 31) * 4;
        float cwv[4], swv[4];
#pragma unroll
        for (int c = 0; c < 4; ++c) {
            const int k = (i * (wbase + c)) & 127;
            cwv[c] = ct[k];
            swv[c] = st[k];
        }

        f32x4* const o1 = (f32x4*)out + (size_t)(b * 128 + i) * 4096;
        f32x4* const o2 = (f32x4*)out + (size_t)(b * 128 + (128 - i)) * 4096;
        const bool dup = (i >= 1 && i <= 63);

#pragma unroll
        for (int j = 0; j < 16; ++j) {
            const int q  = t + j * 256;       // float4 index in plane, coalesced
            const int hh = q >> 5;            // 2 distinct rows per wave -> broadcast LDS reads
            const float a  = arL[ii][hh];
            const float bb = aiL[ii][hh];
            f32x4 v;
            v.x = fmaf(a, cwv[0], -bb * swv[0]);
            v.y = fmaf(a, cwv[1], -bb * swv[1]);
            v.z = fmaf(a, cwv[2], -bb * swv[2]);
            v.w = fmaf(a, cwv[3], -bb * swv[3]);
            o1[q] = v;
            if (dup) o2[q] = v;
        }
    }
}

extern "C" void kernel_launch(void* const* d_in, const int* in_sizes, int n_in,
                              void* d_out, int out_size, void* d_ws, size_t ws_size,
                              hipStream_t stream) {
    const float* x = (const float*)d_in[0];   // (32,1,128,128) f32; mask unused
    float* out = (float*)d_out;               // (32,128,128,128) f32
    kspace_v4<<<dim3(1024), dim3(256), 0, stream>>>(x, out);
}

// Round 6
// 51.438 us; speedup vs baseline: 1.2546x; 1.2546x over previous
//
#include <hip/hip_runtime.h>
#include <math.h>

// out[b,i,h,w] = Ar[b,h,i]*cos(2*pi*i*w/128)/128 - Ai[b,h,i]*sin(2*pi*i*w/128)/128
// A = row-DFT of x (fft2 + ifft over H == fft over W). mask unused.
// x real => out[b,128-i] == out[b,i] EXACTLY: compute i=0..64, store mirrors.
//
// v5 lessons applied: single store stream per wave at a time (v3/v4's
// interleaved dual-plane stores regressed); x in registers (exclusive per
// thread, LDS staging was overhead); DFT trig = LDS table + incremental
// phase index (2-way broadcast reads are free); exactly 2 barriers; no
// nontemporal stores; no forced occupancy (spill-safe 256-VGPR cap).
// Grid: 512 = 32 b x 16 groups. Group g: planes {4g..4g+3} (+ i=64 for g=0);
// every block stores exactly 8 planes of 64 KB.

typedef float f32x4 __attribute__((ext_vector_type(4)));

__global__ __launch_bounds__(256, 2) void kspace_v5(const float* __restrict__ x,
                                                    float* __restrict__ out) {
    const int blk  = blockIdx.x;       // 0..511
    const int b    = blk >> 4;
    const int g    = blk & 15;
    const int t    = threadIdx.x;
    const int wv   = t >> 6;           // wave 0..3
    const int lane = t & 63;
    const int h    = wv * 32 + (lane >> 1);   // this thread's DFT row
    const int half = lane & 1;                // which 64-sample half

    __shared__ __align__(16) float ct[128], st[128];          // cos/sin(2*pi*k/128)
    __shared__ __align__(16) float arL[5][128], aiL[5][128];  // A/W per plane slot

    if (t < 128) {
        float s, c;
        sincospif((float)t * (1.0f / 64.0f), &s, &c);   // angle pi*(t/64)
        ct[t] = c;
        st[t] = s;
    }

    // ---- my half-row (64 floats, 256 B contiguous) into registers ----
    const float* xp = x + ((size_t)b * 128 + h) * 128 + half * 64;
    float xs[64];
#pragma unroll
    for (int j = 0; j < 16; ++j) {
        const f32x4 v = ((const f32x4*)xp)[j];
        xs[4 * j + 0] = v.x;
        xs[4 * j + 1] = v.y;
        xs[4 * j + 2] = v.z;
        xs[4 * j + 3] = v.w;
    }
    __syncthreads();   // trig table ready

    const int nP = (g == 0) ? 5 : 4;

    // ---- DFT phase: A[i][h] = sum_u x[h][u] * e^{-2*pi*I*i*u/128} ----
#pragma unroll 1
    for (int ii = 0; ii < nP; ++ii) {
        const int i = (ii < 4) ? (g * 4 + ii) : 64;
        int k = (i * half * 64) & 127;        // phase index at u0 = half*64
        float cacc = 0.0f, sacc = 0.0f;
#pragma unroll
        for (int j = 0; j < 64; ++j) {        // k lane-uniform up to `half`:
            const float xv = xs[j];           // 2-addr broadcast LDS reads (free)
            cacc = fmaf(xv, ct[k], cacc);
            sacc = fmaf(xv, st[k], sacc);
            k = (k + i) & 127;
        }
        cacc += __shfl_xor(cacc, 1);          // combine the pair's half-sums
        sacc += __shfl_xor(sacc, 1);
        if (half == 0) {
            arL[ii][h] =  cacc * (1.0f / 128.0f);
            aiL[ii][h] = -sacc * (1.0f / 128.0f);   // Im(fft) = -sum x*sin
        }
    }
    __syncthreads();   // A ready; no further barriers

    // ---- store phase: 8 planes per block, one stream at a time ----
#pragma unroll 1
    for (int ii = 0; ii < nP; ++ii) {
        const int i = (ii < 4) ? (g * 4 + ii) : 64;

        // per-lane trig for its fixed 4 w-columns (exact table values)
        const int wbase = (lane & 31) * 4;
        float cwv[4], swv[4];
#pragma unroll
        for (int c = 0; c < 4; ++c) {
            const int k2 = (i * (wbase + c)) & 127;
            cwv[c] = ct[k2];
            swv[c] = st[k2];
        }

        const int npass = (i == 0 || i == 64) ? 1 : 2;
#pragma unroll 1
        for (int p = 0; p < npass; ++p) {
            const int plane = p ? (128 - i) : i;
            f32x4* const o = (f32x4*)out + (size_t)(b * 128 + plane) * 4096;
#pragma unroll
            for (int j = 0; j < 16; ++j) {
                const int q  = t + j * 256;   // coalesced float4 index in plane
                const int hh = q >> 5;        // 2 rows per wave -> broadcast reads
                const float a  = arL[ii][hh];
                const float bb = aiL[ii][hh];
                f32x4 v;
                v.x = fmaf(a, cwv[0], -bb * swv[0]);
                v.y = fmaf(a, cwv[1], -bb * swv[1]);
                v.z = fmaf(a, cwv[2], -bb * swv[2]);
                v.w = fmaf(a, cwv[3], -bb * swv[3]);
                o[q] = v;
            }
        }
    }
}

extern "C" void kernel_launch(void* const* d_in, const int* in_sizes, int n_in,
                              void* d_out, int out_size, void* d_ws, size_t ws_size,
                              hipStream_t stream) {
    const float* x = (const float*)d_in[0];   // (32,1,128,128) f32; mask unused
    float* out = (float*)d_out;               // (32,128,128,128) f32
    kspace_v5<<<dim3(512), dim3(256), 0, stream>>>(x, out);
}

// Round 7
// 49.906 us; speedup vs baseline: 1.2931x; 1.0307x over previous
//
#include <hip/hip_runtime.h>
#include <math.h>

// out[b,i,h,w] = Ar[b,h,i]*cos(2*pi*i*w/128)/128 - Ai[b,h,i]*sin(2*pi*i*w/128)/128
// A = row-DFT of x (fft2 + ifft over H == fft over W). mask unused.
// x real => out[b,128-i] == out[b,i] EXACTLY: compute i=0..64, store mirrors.
//
// v6: ZERO LDS, ZERO barriers. x half-row in registers; DFT via in-register
// complex rotation (v3-proven numerics); A handed to the store loop by 2
// __shfl's per iter (wave wv stores rows [32wv,32wv+32) so the A owner is in
// the same wave); planes software-pipelined: stores of plane p interleave
// with DFT of plane p+1, store queue never drained (no syncthreads -> no
// vmcnt(0) in the stream). Plain coalesced 1KB-per-instruction stores.
// Grid: 1024 = 32 b x 32 groups; group g: planes {2g,2g+1} (+64 for g=0).

typedef float f32x4 __attribute__((ext_vector_type(4)));

__device__ __forceinline__ void dft_plane(const float* xs, int i, int half,
                                          float& arO, float& aiO) {
    // rotation step e^{-I*2*pi*i/128}
    float sstep, cstep;
    sincospif((float)i * (1.0f / 64.0f), &sstep, &cstep);
    const float dc = cstep, ds = -sstep;
    float ar = 0.0f, ai = 0.0f;
#pragma unroll
    for (int ch = 0; ch < 2; ++ch) {
        const int u0 = half * 64 + ch * 32;
        const int a0 = (i * u0) & 127;           // exact mod-128 phase re-init
        float s0, c0;
        sincospif((float)a0 * (1.0f / 64.0f), &s0, &c0);
        float cr = c0, ci = -s0;                 // e^{-I*theta(u0)}
#pragma unroll
        for (int j2 = 0; j2 < 32; ++j2) {
            const float xv = xs[ch * 32 + j2];
            ar = fmaf(xv, cr, ar);
            ai = fmaf(xv, ci, ai);
            const float ncr = fmaf(cr, dc, -ci * ds);
            ci = fmaf(cr, ds, ci * dc);
            cr = ncr;
        }
    }
    ar += __shfl_xor(ar, 1);                     // pair combine: both lanes hold sum
    ai += __shfl_xor(ai, 1);
    arO = ar * (1.0f / 128.0f);
    aiO = ai * (1.0f / 128.0f);
}

__global__ __launch_bounds__(256) void kspace_v6(const float* __restrict__ x,
                                                 float* __restrict__ out) {
    const int blk  = blockIdx.x;       // 0..1023
    const int b    = blk >> 5;
    const int g    = blk & 31;
    const int t    = threadIdx.x;
    const int wv   = t >> 6;           // wave 0..3 -> DFT+store rows [32wv,32wv+32)
    const int lane = t & 63;
    const int h    = wv * 32 + (lane >> 1);   // this thread's DFT row
    const int half = lane & 1;                // which 64-sample half

    // ---- my half-row (64 floats, 256 B contiguous) into registers ----
    const float* xp = x + ((size_t)b * 128 + h) * 128 + half * 64;
    float xs[64];
#pragma unroll
    for (int j = 0; j < 16; ++j) {
        const f32x4 v = ((const f32x4*)xp)[j];
        xs[4 * j + 0] = v.x;
        xs[4 * j + 1] = v.y;
        xs[4 * j + 2] = v.z;
        xs[4 * j + 3] = v.w;
    }

    const int nP = (g == 0) ? 3 : 2;   // planes: {2g, 2g+1} (+ 64 for g=0)

    // peel DFT of first plane
    float arC, aiC;
    dft_plane(xs, 2 * g, half, arC, aiC);

#pragma unroll 1
    for (int p = 0; p < nP; ++p) {
        const int i = (p < 2) ? (2 * g + p) : 64;

        // per-lane trig for its 4 fixed w-columns: w = 4*(lane&31)+c
        const int wbase = (lane & 31) * 4;
        float cwv[4], swv[4];
#pragma unroll
        for (int c = 0; c < 4; ++c) {
            const int k = (i * (wbase + c)) & 127;
            sincospif((float)k * (1.0f / 64.0f), &swv[c], &cwv[c]);
        }

        const int npass = (i == 0 || i == 64) ? 1 : 2;
#pragma unroll 1
        for (int pass = 0; pass < npass; ++pass) {
            const int pl = pass ? (128 - i) : i;
            f32x4* const o = (f32x4*)out + (size_t)(b * 128 + pl) * 4096;
#pragma unroll
            for (int j = 0; j < 16; ++j) {
                // wave wv writes f32x4 q = wv*1024 + 64j + lane (1KB/instr, coalesced)
                // row hh = q>>5 = 32wv + 2j + (lane>>5); A owner lane = 2*(2j+(lane>>5))
                const int src = 4 * j + 2 * (lane >> 5);
                const float a  = __shfl(arC, src);
                const float bb = __shfl(aiC, src);
                f32x4 v;
                v.x = fmaf(a, cwv[0], -bb * swv[0]);
                v.y = fmaf(a, cwv[1], -bb * swv[1]);
                v.z = fmaf(a, cwv[2], -bb * swv[2]);
                v.w = fmaf(a, cwv[3], -bb * swv[3]);
                o[wv * 1024 + j * 64 + lane] = v;
            }
        }

        // DFT of next plane, overlapped with the in-flight stores above
        if (p + 1 < nP) {
            const int inext = (p + 1 < 2) ? (2 * g + p + 1) : 64;
            float arN, aiN;
            dft_plane(xs, inext, half, arN, aiN);
            arC = arN;
            aiC = aiN;
        }
    }
}

extern "C" void kernel_launch(void* const* d_in, const int* in_sizes, int n_in,
                              void* d_out, int out_size, void* d_ws, size_t ws_size,
                              hipStream_t stream) {
    const float* x = (const float*)d_in[0];   // (32,1,128,128) f32; mask unused
    float* out = (float*)d_out;               // (32,128,128,128) f32
    kspace_v6<<<dim3(1024), dim3(256), 0, stream>>>(x, out);
}